// Round 4
// baseline (166.827 us; speedup 1.0000x reference)
//
#include <hip/hip_runtime.h>
#include <math.h>

#define NB 4
#define HH 16
#define SS 1024
#define DD 64
#define KBLK 128

typedef __attribute__((ext_vector_type(8))) short bf16x8;
typedef __attribute__((ext_vector_type(4))) float f32x4;

static __device__ __forceinline__ short f2bf(float f) {
    __bf16 h = (__bf16)f;
    return __builtin_bit_cast(short, h);
}
static __device__ __forceinline__ float bflo(int w) {
    return __builtin_bit_cast(float, (unsigned)w << 16);
}
static __device__ __forceinline__ float bfhi(int w) {
    return __builtin_bit_cast(float, (unsigned)w & 0xffff0000u);
}
// P LDS: [pos = q*128 + k][16 h] bf16 as 8 u32 head-pairs, XOR swizzle.
// writer: 2-way (free); reader (phase1.5, b32): conflict-free.
static __device__ __forceinline__ int pidx(int pos, int h) {
    int s = ((pos >> 2) & 3) | (((pos >> 9) & 1) << 2);
    return pos * 8 + (h ^ s);
}
// M LDS: per-g region of 1024 u32 (16 q x 64 k-pairs), swizzle on 16B groups.
// writer b64 and reader b128 both uniform 8 lanes/bank-group (optimal).
static __device__ __forceinline__ int midx(int g, int loc, int x3) {
    return g * 1024 + ((((loc >> 2) ^ x3) << 2) | (loc & 3));
}

static __device__ __forceinline__ bf16x8 load8_bf16(const float* p) {
    const float4* p4 = reinterpret_cast<const float4*>(p);
    float4 a = p4[0], b = p4[1];
    bf16x8 f;
    f[0]=f2bf(a.x); f[1]=f2bf(a.y); f[2]=f2bf(a.z); f[3]=f2bf(a.w);
    f[4]=f2bf(b.x); f[5]=f2bf(b.y); f[6]=f2bf(b.z); f[7]=f2bf(b.w);
    return f;
}

// ---------- prep: f32 -> bf16 copy (K) ----------
__global__ __launch_bounds__(256) void prep_bf16(const float* __restrict__ x,
                                                 short* __restrict__ y, int n8) {
    int i = blockIdx.x * 256 + threadIdx.x;
    if (i >= n8) return;
    *(reinterpret_cast<bf16x8*>(y) + i) = load8_bf16(x + (size_t)i * 8);
}

// ---------- prep: V [B,H,S,D] f32 -> V^T [B,H,D,S] bf16 ----------
__global__ __launch_bounds__(256) void prep_vT(const float* __restrict__ xv,
                                               short* __restrict__ vT) {
    __shared__ float T[64][65];
    int bid = blockIdx.x;
    int bh = bid >> 4, st = bid & 15;
    const float* src = xv + ((size_t)bh * SS + st * 64) * DD;
    int t = threadIdx.x;
#pragma unroll
    for (int r = 0; r < 4; ++r) {
        int s = r * 16 + (t >> 4), d = (t & 15) * 4;
        float4 v = *reinterpret_cast<const float4*>(src + s * DD + d);
        T[s][d] = v.x; T[s][d+1] = v.y; T[s][d+2] = v.z; T[s][d+3] = v.w;
    }
    __syncthreads();
#pragma unroll
    for (int r = 0; r < 4; ++r) {
        int d = r * 16 + (t >> 4), s0 = (t & 15) * 4;
        ushort4 o;
        o.x = (ushort)f2bf(T[s0][d]);   o.y = (ushort)f2bf(T[s0+1][d]);
        o.z = (ushort)f2bf(T[s0+2][d]); o.w = (ushort)f2bf(T[s0+3][d]);
        *reinterpret_cast<ushort4*>(vT + ((size_t)bh * DD + d) * SS + st * 64 + s0) = o;
    }
}

// One block = (b, 16-row q-tile), 16 waves, KBLK=128 per step, 2 barriers/step.
//  phase1  : wave (hp=w&7, kh=w>>3): QK^T for heads {2hp,2hp+1}, kt in [4kh,4kh+4) -> P
//  phase1.5: wave w: mix via MFMA for q-row w, all 128 k, all 16 g -> M
//  phase2  : wave w: softmax (log2) + PV for head g=w  [fused with next phase1]
__global__ __launch_bounds__(1024, 4) void hca_fused(
    const float* __restrict__ xq, const short* __restrict__ kbf,
    const short* __restrict__ vT, const float* __restrict__ Wm,
    const int* __restrict__ causalp, float* __restrict__ out)
{
    __shared__ int Pbuf[16384];   // 64 KB
    __shared__ int Mbuf[16384];   // 64 KB

    const int tid  = threadIdx.x;
    const int lane = tid & 63;
    const int w    = tid >> 6;
    const int l15  = lane & 15;
    const int lg   = lane >> 4;

    const int bid = blockIdx.x;
    const int b   = bid & 3;       // one b per XCD -> K/V L2-resident
    const int qt  = bid >> 2;
    const int q0  = qt << 4;

    const int causal = causalp[0];
    const int hp = w & 7;
    const int kh = w >> 3;
    const int g  = w;

    const float LOG2E = 1.44269504088896f;

    // W B-frag for the mix MFMA (K=16 used, zero-padded)
    bf16x8 wt = {0,0,0,0,0,0,0,0};
    if (lg < 2) {
#pragma unroll
        for (int i = 0; i < 8; ++i)
            wt[i] = f2bf(Wm[l15 * 16 + lg * 8 + i] * 0.125f * LOG2E);
    }

    // Q A-frags for phase-1 head pair
    bf16x8 qf[2][2];
#pragma unroll
    for (int hi = 0; hi < 2; ++hi) {
        const float* qp = xq + ((size_t)(b * HH + 2 * hp + hi) * SS + q0 + l15) * DD + lg * 8;
#pragma unroll
        for (int ds = 0; ds < 2; ++ds) qf[hi][ds] = load8_bf16(qp + ds * 32);
    }

    f32x4 oacc[4];
#pragma unroll
    for (int nt = 0; nt < 4; ++nt) oacc[nt] = (f32x4){0.f, 0.f, 0.f, 0.f};
    float mrun = -INFINITY, lrun = 0.f;

    const short* kb0 = kbf + (size_t)(b * HH + 2 * hp) * SS * DD;
    const short* vb  = vT  + (size_t)(b * HH + g) * DD * SS;

    const int nk = causal ? ((q0 + 16 + KBLK - 1) >> 7) : (SS / KBLK);
    const int xw = (w + l15) & 7;   // M swizzle bits (writer & reader share form)

    for (int kst = 0; kst < nk; ++kst) {
        const int k0 = kst << 7;

        // ---------- phase1: scores for 2 heads x 16q x 64k-slice ----------
#pragma unroll
        for (int kt2 = 0; kt2 < 4; ++kt2) {
            const int kt = kh * 4 + kt2;
            const short* kra = kb0 + (size_t)(k0 + kt * 16 + l15) * DD + lg * 8;
            f32x4 a0 = (f32x4){0.f,0.f,0.f,0.f}, a1 = a0;
#pragma unroll
            for (int ds = 0; ds < 2; ++ds) {
                bf16x8 kfa = *reinterpret_cast<const bf16x8*>(kra + ds * 32);
                bf16x8 kfb = *reinterpret_cast<const bf16x8*>(kra + (size_t)SS * DD + ds * 32);
                a0 = __builtin_amdgcn_mfma_f32_16x16x32_bf16(qf[0][ds], kfa, a0, 0, 0, 0);
                a1 = __builtin_amdgcn_mfma_f32_16x16x32_bf16(qf[1][ds], kfb, a1, 0, 0, 0);
            }
#pragma unroll
            for (int r = 0; r < 4; ++r) {
                int pos = (lg * 4 + r) * KBLK + kt * 16 + l15;
                int pk = (int)(unsigned short)f2bf(a0[r]) | ((int)(unsigned short)f2bf(a1[r]) << 16);
                Pbuf[pidx(pos, hp)] = pk;
            }
        }
        __syncthreads();   // sync1: P ready; also orders prev-step M-reads vs M-writes below

        // ---------- phase1.5: head-mix MFMA; wave w -> q-row w ----------
#pragma unroll
        for (int m = 0; m < 8; ++m) {
            const int c = w * 8 + m;
            const int pos = c * 16 + l15;
            int4 ia = {0, 0, 0, 0};
            if (lg < 2) {
                ia.x = Pbuf[pidx(pos, lg * 4 + 0)];
                ia.y = Pbuf[pidx(pos, lg * 4 + 1)];
                ia.z = Pbuf[pidx(pos, lg * 4 + 2)];
                ia.w = Pbuf[pidx(pos, lg * 4 + 3)];
            }
            bf16x8 A = __builtin_bit_cast(bf16x8, ia);
            f32x4 cc = (f32x4){0.f, 0.f, 0.f, 0.f};
            cc = __builtin_amdgcn_mfma_f32_16x16x32_bf16(A, wt, cc, 0, 0, 0);
            // lane: g=l15, k = m*16 + lg*4 + r (q-row = w)
            int u0 = (int)(unsigned short)f2bf(cc[0]) | ((int)(unsigned short)f2bf(cc[1]) << 16);
            int u1 = (int)(unsigned short)f2bf(cc[2]) | ((int)(unsigned short)f2bf(cc[3]) << 16);
            int loc = w * 64 + m * 8 + lg * 2;      // u32 index inside g-region
            *reinterpret_cast<int2*>(&Mbuf[midx(l15, loc, xw)]) = make_int2(u0, u1);
        }
        __syncthreads();   // sync2: M ready

        // ---------- phase2: softmax + PV for head g (fuses with next phase1) ----------
        float sm[32];
#pragma unroll
        for (int kc = 0; kc < 4; ++kc) {
            int loc = l15 * 64 + kc * 16 + lg * 4;
            int4 rr = *reinterpret_cast<const int4*>(&Mbuf[midx(g, loc, xw)]);
#pragma unroll
            for (int j = 0; j < 4; ++j) {
                sm[kc * 8 + 2 * j]     = bflo(rr[j]);
                sm[kc * 8 + 2 * j + 1] = bfhi(rr[j]);
            }
        }
        if (causal && kst == nk - 1) {
#pragma unroll
            for (int jj = 0; jj < 32; ++jj) {
                int kk = (jj >> 3) * 32 + lg * 8 + (jj & 7);
                if (k0 + kk > q0 + l15) sm[jj] = -INFINITY;
            }
        }

        float mx[8];
#pragma unroll
        for (int t = 0; t < 8; ++t)
            mx[t] = fmaxf(fmaxf(sm[4*t], sm[4*t+1]), fmaxf(sm[4*t+2], sm[4*t+3]));
        float mt = fmaxf(fmaxf(fmaxf(mx[0], mx[1]), fmaxf(mx[2], mx[3])),
                         fmaxf(fmaxf(mx[4], mx[5]), fmaxf(mx[6], mx[7])));
        mt = fmaxf(mt, __shfl_xor(mt, 16));
        mt = fmaxf(mt, __shfl_xor(mt, 32));

        if (__any(mt > mrun + 8.0f)) {            // defer-rescale
            float mnew = fmaxf(mrun, mt);
            float scl = __builtin_amdgcn_exp2f(mrun - mnew);
            mrun = mnew;
            lrun *= scl;
            int scli = __builtin_bit_cast(int, scl);
#pragma unroll
            for (int r = 0; r < 4; ++r) {
                int v = __builtin_amdgcn_ds_bpermute((lg * 4 + r) * 4, scli);
                float s = __builtin_bit_cast(float, v);
#pragma unroll
                for (int nt = 0; nt < 4; ++nt) oacc[nt][r] *= s;
            }
        }

#pragma unroll
        for (int jj = 0; jj < 32; ++jj) sm[jj] = __builtin_amdgcn_exp2f(sm[jj] - mrun);
        float psum = 0.f;
#pragma unroll
        for (int jj = 0; jj < 32; ++jj) psum += sm[jj];
        lrun += psum;

#pragma unroll
        for (int kc = 0; kc < 4; ++kc) {
            int paw[4];
#pragma unroll
            for (int j = 0; j < 4; ++j)
                paw[j] = (int)(unsigned short)f2bf(sm[kc*8 + 2*j])
                       | ((int)(unsigned short)f2bf(sm[kc*8 + 2*j + 1]) << 16);
            bf16x8 pa = __builtin_bit_cast(bf16x8, *(int4*)paw);
#pragma unroll
            for (int nt = 0; nt < 4; ++nt) {
                bf16x8 vf = *reinterpret_cast<const bf16x8*>(
                    vb + (size_t)(nt * 16 + l15) * SS + k0 + kc * 32 + lg * 8);
                oacc[nt] = __builtin_amdgcn_mfma_f32_16x16x32_bf16(pa, vf, oacc[nt], 0, 0, 0);
            }
        }
        // no trailing barrier: next phase1 writes Pbuf (reads of Pbuf ended pre-sync2);
        // next phase1.5's M-writes are fenced from this phase2's M-reads by sync1(t+1).
    }

    // ---------- epilogue ----------
    float lt = lrun;
    lt += __shfl_xor(lt, 16);
    lt += __shfl_xor(lt, 32);
    int lti = __builtin_bit_cast(int, lt);
#pragma unroll
    for (int r = 0; r < 4; ++r) {
        int v = __builtin_amdgcn_ds_bpermute((lg * 4 + r) * 4, lti);
        float linv = 1.0f / __builtin_bit_cast(float, v);
        int q = lg * 4 + r;
#pragma unroll
        for (int nt = 0; nt < 4; ++nt)
            out[((size_t)(b * SS + q0 + q) * HH + g) * DD + nt * 16 + l15] =
                oacc[nt][r] * linv;
    }
}

extern "C" void kernel_launch(void* const* d_in, const int* in_sizes, int n_in,
                              void* d_out, int out_size, void* d_ws, size_t ws_size,
                              hipStream_t stream) {
    const float* xq = (const float*)d_in[0];
    const float* xk = (const float*)d_in[1];
    const float* xv = (const float*)d_in[2];
    const float* Wm = (const float*)d_in[3];
    const int* causal = (const int*)d_in[4];
    float* out = (float*)d_out;

    short* vT  = (short*)d_ws;                       // 8 MB bf16 V^T
    short* kbf = vT + (size_t)NB * HH * DD * SS;     // 8 MB bf16 K

    const int n8 = NB * HH * SS * DD / 8;
    prep_bf16<<<(n8 + 255) / 256, 256, 0, stream>>>(xk, kbf, n8);
    prep_vT<<<NB * HH * (SS / 64), 256, 0, stream>>>(xv, vT);

    hca_fused<<<NB * (SS / 16), 1024, 0, stream>>>(xq, kbf, vT, Wm, causal, out);
}

// Round 5
// 87.750 us; speedup vs baseline: 1.9012x; 1.9012x over previous
//
#include <hip/hip_runtime.h>
#include <math.h>

#define NB 4
#define HH 16
#define SS 1024
#define DD 64
#define NKST 16   // SS / 64

typedef __attribute__((ext_vector_type(8))) short bf16x8;
typedef __attribute__((ext_vector_type(4))) float f32x4;

static __device__ __forceinline__ short f2bf(float f) {
    __bf16 h = (__bf16)f;
    return __builtin_bit_cast(short, h);
}
static __device__ __forceinline__ float bflo(int w) {
    return __builtin_bit_cast(float, (unsigned)w << 16);
}
static __device__ __forceinline__ float bfhi(int w) {
    return __builtin_bit_cast(float, (unsigned)w & 0xffff0000u);
}
// P LDS: [pos = q*64 + k][8 u32 head-pairs], XOR swizzle.
// writer 2-way (free), phase-1.5 reader conflict-free (derived in journal).
static __device__ __forceinline__ int pidx(int pos, int hp) {
    int s = ((pos >> 2) & 3) | (((pos >> 9) & 1) << 2);
    return pos * 8 + (hp ^ s);
}
// M LDS: [8 g_local][16 q x 32 k-pairs u32], XOR on 16B groups (R4-measured-fine).
static __device__ __forceinline__ int midx(int gl, int loc, int x3) {
    return gl * 512 + ((((loc >> 2) ^ x3) << 2) | (loc & 3));
}

static __device__ __forceinline__ bf16x8 load8_bf16(const float* p) {
    const float4* p4 = reinterpret_cast<const float4*>(p);
    float4 a = p4[0], b = p4[1];
    bf16x8 f;
    f[0]=f2bf(a.x); f[1]=f2bf(a.y); f[2]=f2bf(a.z); f[3]=f2bf(a.w);
    f[4]=f2bf(b.x); f[5]=f2bf(b.y); f[6]=f2bf(b.z); f[7]=f2bf(b.w);
    return f;
}

// ---------- prep: K -> fragment-major bf16 ----------
// chunk c = ((((b*16+h)*16+kst)*4+kt)*2+ds)*64 + lane ; 16B per chunk.
__global__ __launch_bounds__(256) void prep_kfrag(const float* __restrict__ xk,
                                                  short* __restrict__ kfr) {
    int c = blockIdx.x * 256 + threadIdx.x;          // < 524288
    int lane = c & 63, ds = (c >> 6) & 1, kt = (c >> 7) & 3;
    int kst = (c >> 9) & 15, h = (c >> 13) & 15, b = c >> 17;
    const float* src = xk + ((size_t)((b * HH + h) * SS) + kst * 64 + kt * 16 + (lane & 15)) * DD
                          + ds * 32 + (lane >> 4) * 8;
    *(reinterpret_cast<bf16x8*>(kfr) + c) = load8_bf16(src);
}

// ---------- prep: V -> fragment-major bf16 (transposed), via LDS tile ----------
// chunk c = ((((b*16+h)*16+kst)*2+kc)*4+nt)*64 + lane ; element i of chunk =
// V[b][h][kst*64 + kc*32 + (lane>>4)*8 + i][nt*16 + (lane&15)]
__global__ __launch_bounds__(256) void prep_vfrag(const float* __restrict__ xv,
                                                  short* __restrict__ vfr) {
    __shared__ float T[64][65];
    int tile = blockIdx.x;                 // (b*16+h)*16 + kst
    int t = threadIdx.x;
    const float* src = xv + ((size_t)(tile >> 4) * SS + (tile & 15) * 64) * DD;
    int row = t >> 2, col = (t & 3) * 16;
#pragma unroll
    for (int ii = 0; ii < 4; ++ii) {
        float4 v = *reinterpret_cast<const float4*>(src + row * DD + col + ii * 4);
        T[row][col + ii*4] = v.x; T[row][col + ii*4 + 1] = v.y;
        T[row][col + ii*4 + 2] = v.z; T[row][col + ii*4 + 3] = v.w;
    }
    __syncthreads();
#pragma unroll
    for (int jj = 0; jj < 2; ++jj) {
        int c2 = t * 2 + jj;                         // 0..511
        int lane = c2 & 63, nt = (c2 >> 6) & 3, kc = (c2 >> 8) & 1;
        bf16x8 o;
#pragma unroll
        for (int i = 0; i < 8; ++i)
            o[i] = f2bf(T[kc * 32 + (lane >> 4) * 8 + i][nt * 16 + (lane & 15)]);
        *(reinterpret_cast<bf16x8*>(vfr) + (size_t)tile * 512 + c2) = o;
    }
}

// One block = (b, 16-row q-tile, half). 8 waves. KBLK=64, 2 barriers/step.
//  phase1  : wave w: QK^T for heads {2w,2w+1}, all 4 kt -> P (coalesced frag loads)
//  phase1.5: wave w: mix MFMA for pos-chunks, store this half's 8 heads -> M
//  phase2  : wave w: softmax + PV for head g = half*8 + w
__global__ __launch_bounds__(512, 4) void hca_fused(
    const float* __restrict__ xq, const short* __restrict__ kfr,
    const short* __restrict__ vfr, const float* __restrict__ Wm,
    const int* __restrict__ causalp, float* __restrict__ out)
{
    __shared__ int Pbuf[8192];   // 32 KB
    __shared__ int Mbuf[4096];   // 16 KB

    const int tid  = threadIdx.x;
    const int lane = tid & 63;
    const int w    = tid >> 6;     // 0..7
    const int l15  = lane & 15;
    const int lg   = lane >> 4;

    // round 0 (bids 0..255): half 0, qt descending; round 1: half 1, qt ascending.
    // CU c tends to get bids c and c+256 -> qt pair sums to 63 (balanced).
    const int bid  = blockIdx.x;
    const int i8   = bid & 255;
    const int rnd  = bid >> 8;
    const int b    = i8 & 3;
    const int jj   = i8 >> 2;
    const int qt   = rnd ? jj : 63 - jj;
    const int half = rnd;
    const int q0   = qt << 4;

    const int causal = causalp[0];
    const int g  = half * 8 + w;   // phase-2 output head

    const float LOG2E = 1.44269504088896f;

    // W B-frag for mix MFMA (K=16 used, zero-padded)
    bf16x8 wt = {0,0,0,0,0,0,0,0};
    if (lg < 2) {
#pragma unroll
        for (int i = 0; i < 8; ++i)
            wt[i] = f2bf(Wm[l15 * 16 + lg * 8 + i] * 0.125f * LOG2E);
    }

    // Q A-frags for phase-1 heads (2w, 2w+1)
    bf16x8 qf[2][2];
#pragma unroll
    for (int hi = 0; hi < 2; ++hi) {
        const float* qp = xq + ((size_t)(b * HH + 2 * w + hi) * SS + q0 + l15) * DD + lg * 8;
#pragma unroll
        for (int ds = 0; ds < 2; ++ds) qf[hi][ds] = load8_bf16(qp + ds * 32);
    }

    f32x4 oacc[4];
#pragma unroll
    for (int nt = 0; nt < 4; ++nt) oacc[nt] = (f32x4){0.f, 0.f, 0.f, 0.f};
    float mrun = -INFINITY, lrun = 0.f;

    const int nk = causal ? ((q0 + 16 + 63) >> 6) : NKST;

    for (int kst = 0; kst < nk; ++kst) {
        const int k0 = kst << 6;

        // ---------- phase1: QK^T, heads 2w & 2w+1, coalesced frag loads ----------
        const short* kbase = kfr + ((size_t)((b * HH + 2 * w) * NKST + kst) * 8) * 512 + lane * 8;
#pragma unroll
        for (int kt = 0; kt < 4; ++kt) {
            f32x4 a0 = (f32x4){0.f,0.f,0.f,0.f}, a1 = a0;
#pragma unroll
            for (int ds = 0; ds < 2; ++ds) {
                bf16x8 kfa = *reinterpret_cast<const bf16x8*>(kbase + (kt*2 + ds) * 512);
                bf16x8 kfb = *reinterpret_cast<const bf16x8*>(kbase + (NKST*8 + kt*2 + ds) * 512);
                a0 = __builtin_amdgcn_mfma_f32_16x16x32_bf16(qf[0][ds], kfa, a0, 0, 0, 0);
                a1 = __builtin_amdgcn_mfma_f32_16x16x32_bf16(qf[1][ds], kfb, a1, 0, 0, 0);
            }
#pragma unroll
            for (int r = 0; r < 4; ++r) {
                int pos = (lg * 4 + r) * 64 + kt * 16 + l15;
                int pk = (int)(unsigned short)f2bf(a0[r]) | ((int)(unsigned short)f2bf(a1[r]) << 16);
                Pbuf[pidx(pos, w)] = pk;
            }
        }

        // V prefetch (global, coalesced; no LDS hazard -> before sync1;
        // first use is after sync2 -> latency hidden under mix + barriers)
        const short* vbase = vfr + ((size_t)((b * HH + g) * NKST + kst) * 8) * 512 + lane * 8;
        bf16x8 vf[8];
#pragma unroll
        for (int kc = 0; kc < 2; ++kc)
#pragma unroll
            for (int nt = 0; nt < 4; ++nt)
                vf[kc * 4 + nt] = *reinterpret_cast<const bf16x8*>(vbase + (kc*4 + nt) * 512);

        __syncthreads();   // sync1: P ready (also orders prev phase2 M-reads vs M-writes)

        // ---------- phase1.5: head-mix MFMA ----------
#pragma unroll
        for (int m = 0; m < 8; ++m) {
            const int c = w * 8 + m;               // 16-pos chunk; q = c>>2
            const int pos = c * 16 + l15;
            int4 ia = {0, 0, 0, 0};
            if (lg < 2) {
                ia.x = Pbuf[pidx(pos, lg * 4 + 0)];
                ia.y = Pbuf[pidx(pos, lg * 4 + 1)];
                ia.z = Pbuf[pidx(pos, lg * 4 + 2)];
                ia.w = Pbuf[pidx(pos, lg * 4 + 3)];
            }
            bf16x8 A = __builtin_bit_cast(bf16x8, ia);
            f32x4 cc = (f32x4){0.f, 0.f, 0.f, 0.f};
            cc = __builtin_amdgcn_mfma_f32_16x16x32_bf16(A, wt, cc, 0, 0, 0);
            // lane: g_out = l15; pos = c*16 + lg*4 + r -> q = c>>2, k = (c&3)*16+lg*4+r
            if ((l15 >> 3) == half) {
                int q = c >> 2;
                int loc = q * 32 + (c & 3) * 8 + lg * 2;
                int x3 = (q + l15) & 7;
                int u0 = (int)(unsigned short)f2bf(cc[0]) | ((int)(unsigned short)f2bf(cc[1]) << 16);
                int u1 = (int)(unsigned short)f2bf(cc[2]) | ((int)(unsigned short)f2bf(cc[3]) << 16);
                *reinterpret_cast<int2*>(&Mbuf[midx(l15 & 7, loc, x3)]) = make_int2(u0, u1);
            }
        }
        __syncthreads();   // sync2: M ready

        // ---------- phase2: softmax (log2) + PV for head g ----------
        const int x3r = (l15 + w) & 7;
        int4 rA = *reinterpret_cast<const int4*>(&Mbuf[midx(w, l15 * 32 + lg * 4, x3r)]);
        int4 rB = *reinterpret_cast<const int4*>(&Mbuf[midx(w, l15 * 32 + 16 + lg * 4, x3r)]);

        float sm[16];
#pragma unroll
        for (int j = 0; j < 4; ++j) {
            sm[2*j]     = bflo(rA[j]);  sm[2*j + 1] = bfhi(rA[j]);
            sm[8 + 2*j] = bflo(rB[j]);  sm[9 + 2*j] = bfhi(rB[j]);
        }
        if (causal && kst == nk - 1) {
#pragma unroll
            for (int j = 0; j < 16; ++j) {
                int kk = (j < 8) ? (lg * 8 + j) : (32 + lg * 8 + (j - 8));
                if (k0 + kk > q0 + l15) sm[j] = -INFINITY;
            }
        }

        float mx[4];
#pragma unroll
        for (int t = 0; t < 4; ++t)
            mx[t] = fmaxf(fmaxf(sm[4*t], sm[4*t+1]), fmaxf(sm[4*t+2], sm[4*t+3]));
        float mt = fmaxf(fmaxf(mx[0], mx[1]), fmaxf(mx[2], mx[3]));
        mt = fmaxf(mt, __shfl_xor(mt, 16));
        mt = fmaxf(mt, __shfl_xor(mt, 32));

        if (__any(mt > mrun + 8.0f)) {            // defer-rescale
            float mnew = fmaxf(mrun, mt);
            float scl = __builtin_amdgcn_exp2f(mrun - mnew);
            mrun = mnew;
            lrun *= scl;
            int scli = __builtin_bit_cast(int, scl);
#pragma unroll
            for (int r = 0; r < 4; ++r) {
                int v = __builtin_amdgcn_ds_bpermute((lg * 4 + r) * 4, scli);
                float s = __builtin_bit_cast(float, v);
#pragma unroll
                for (int nt = 0; nt < 4; ++nt) oacc[nt][r] *= s;
            }
        }

        float p[16];
#pragma unroll
        for (int j = 0; j < 16; ++j) p[j] = __builtin_amdgcn_exp2f(sm[j] - mrun);
        float s0 = ((p[0]+p[1]) + (p[2]+p[3])) + ((p[4]+p[5]) + (p[6]+p[7]));
        float s1 = ((p[8]+p[9]) + (p[10]+p[11])) + ((p[12]+p[13]) + (p[14]+p[15]));
        lrun += s0 + s1;

        int paw[8];
#pragma unroll
        for (int t = 0; t < 8; ++t)
            paw[t] = (int)(unsigned short)f2bf(p[2*t]) | ((int)(unsigned short)f2bf(p[2*t+1]) << 16);
        bf16x8 pa0 = __builtin_bit_cast(bf16x8, *(int4*)&paw[0]);
        bf16x8 pa1 = __builtin_bit_cast(bf16x8, *(int4*)&paw[4]);

#pragma unroll
        for (int nt = 0; nt < 4; ++nt) {
            oacc[nt] = __builtin_amdgcn_mfma_f32_16x16x32_bf16(pa0, vf[nt], oacc[nt], 0, 0, 0);
            oacc[nt] = __builtin_amdgcn_mfma_f32_16x16x32_bf16(pa1, vf[4 + nt], oacc[nt], 0, 0, 0);
        }
        // no trailing barrier: next phase1 writes Pbuf (its reads ended before sync2);
        // this step's M-reads are ordered vs next M-writes by sync1(t+1).
    }

    // ---------- epilogue ----------
    float lt = lrun;
    lt += __shfl_xor(lt, 16);
    lt += __shfl_xor(lt, 32);
    int lti = __builtin_bit_cast(int, lt);
#pragma unroll
    for (int r = 0; r < 4; ++r) {
        int v = __builtin_amdgcn_ds_bpermute((lg * 4 + r) * 4, lti);
        float linv = 1.0f / __builtin_bit_cast(float, v);
        int q = lg * 4 + r;
#pragma unroll
        for (int nt = 0; nt < 4; ++nt)
            out[((size_t)(b * SS + q0 + q) * HH + g) * DD + nt * 16 + l15] =
                oacc[nt][r] * linv;
    }
}

extern "C" void kernel_launch(void* const* d_in, const int* in_sizes, int n_in,
                              void* d_out, int out_size, void* d_ws, size_t ws_size,
                              hipStream_t stream) {
    const float* xq = (const float*)d_in[0];
    const float* xk = (const float*)d_in[1];
    const float* xv = (const float*)d_in[2];
    const float* Wm = (const float*)d_in[3];
    const int* causal = (const int*)d_in[4];
    float* out = (float*)d_out;

    short* vfr = (short*)d_ws;                       // 8 MB fragment-major V
    short* kfr = vfr + (size_t)NB * HH * SS * DD;    // 8 MB fragment-major K

    prep_kfrag<<<2048, 256, 0, stream>>>(xk, kfr);
    prep_vfrag<<<NB * HH * NKST, 256, 0, stream>>>(xv, vfr);

    hca_fused<<<512, 512, 0, stream>>>(xq, kfr, vfr, Wm, causal, out);
}